// Round 1
// baseline (1293.149 us; speedup 1.0000x reference)
//
#include <hip/hip_runtime.h>
#include <cstdint>
#include <cstddef>

typedef __attribute__((ext_vector_type(4))) float f32x4;
typedef __attribute__((ext_vector_type(8))) short bf16x8;      // MFMA operand (8 bf16)
typedef __attribute__((ext_vector_type(8))) unsigned short u16x8;
typedef __attribute__((ext_vector_type(4))) float float4v;

// ---- problem dims ----
#define NB   8
#define TIN  200
#define TO1  51
#define VSZ  1024
#define HSZ  512
static constexpr int MJOINT = NB * TIN * TO1;   // 81600
static constexpr int MROWS  = TO1 * NB;         // 408  (rows t*8+n)

// ---- ws layout (bytes) ----
static constexpr size_t B_ENCBF = 0;                       // 1664*512*2
static constexpr size_t B_ENCW  = B_ENCBF + 1664ull*512*2; // 512*512*2
static constexpr size_t B_DECW  = B_ENCW  + 512ull*512*2;
static constexpr size_t B_OUTW  = B_DECW  + 512ull*512*2;  // 1024*512*2
static constexpr size_t B_WIH   = B_OUTW  + 1024ull*512*2; // 3*2048*512*2
static constexpr size_t B_WHH   = B_WIH   + 3ull*2048*512*2;
static constexpr size_t B_X0    = B_WHH   + 3ull*2048*512*2; // 4 x 512*512*2
static constexpr size_t B_X1    = B_X0 + 512ull*512*2;
static constexpr size_t B_X2    = B_X1 + 512ull*512*2;
static constexpr size_t B_X3    = B_X2 + 512ull*512*2;
static constexpr size_t B_GIN   = B_X3 + 512ull*512*2;     // 408*2048*4
static constexpr size_t B_BSUM  = B_GIN + 408ull*2048*4;   // 3*2048*4
static constexpr size_t B_HBUF  = B_BSUM + 3ull*2048*4;    // 2*16*512*2
static constexpr size_t B_BAR   = B_HBUF + 2ull*16*512*2;  // 256
static constexpr size_t B_ENCP  = B_BAR + 256;             // 1664*512*4
static constexpr size_t B_DECP  = B_ENCP + 1664ull*512*4;  // 512*512*4
static constexpr size_t B_ABUF  = B_DECP + 512ull*512*4;   // 81664*512*2

// ---- helpers ----
__device__ __forceinline__ unsigned short f2bf(float f) {
  union { float f; unsigned u; } v; v.f = f;
  unsigned r = v.u + 0x7FFFu + ((v.u >> 16) & 1u);
  return (unsigned short)(r >> 16);
}
__device__ __forceinline__ float fast_tanh(float x) {
  float t = __expf(2.0f * x);          // inf-safe: x>>0 -> 1, x<<0 -> -1
  return 1.0f - 2.0f / (t + 1.0f);
}
__device__ __forceinline__ float fast_sig(float x) {
  return 1.0f / (1.0f + __expf(-x));
}
__device__ __forceinline__ void gll16(const void* g, void* l) {
  __builtin_amdgcn_global_load_lds(
      (const __attribute__((address_space(1))) unsigned int*)g,
      (__attribute__((address_space(3))) unsigned int*)l, 16, 0, 0);
}

// ---------------- fp32 -> bf16 convert (vector x8) ----------------
__global__ __launch_bounds__(256) void cvt_kernel(const float* __restrict__ s,
                                                  unsigned short* __restrict__ d, int n8) {
  int i = blockIdx.x * 256 + threadIdx.x;
  if (i >= n8) return;
  const float4v* sp = (const float4v*)(s + (size_t)i * 8);
  float4v x = sp[0], y = sp[1];
  u16x8 o;
  o[0]=f2bf(x[0]); o[1]=f2bf(x[1]); o[2]=f2bf(x[2]); o[3]=f2bf(x[3]);
  o[4]=f2bf(y[0]); o[5]=f2bf(y[1]); o[6]=f2bf(y[2]); o[7]=f2bf(y[3]);
  *(u16x8*)(d + (size_t)i * 8) = o;
}

// ---------------- bias sum: bsum = b_ih + b_hh ----------------
__global__ __launch_bounds__(256) void bsum_kernel(const float* __restrict__ a,
                                                   const float* __restrict__ b,
                                                   float* __restrict__ o, int n) {
  int i = blockIdx.x * 256 + threadIdx.x;
  if (i < n) o[i] = a[i] + b[i];
}

// ---------------- embedding gather -> bf16 x0[t*8+n][512] ----------------
__global__ __launch_bounds__(256) void embed_kernel(const float* __restrict__ emb,
                                                    const int* __restrict__ tgt,
                                                    unsigned short* __restrict__ x0) {
  int idx = blockIdx.x * 256 + threadIdx.x;   // 408*64
  if (idx >= MROWS * 64) return;
  int m = idx >> 6, kc = (idx & 63) * 8;
  int t = m >> 3, n = m & 7;
  int v = tgt[n * TO1 + t];
  const float4v* sp = (const float4v*)(emb + (size_t)v * 512 + kc);
  float4v x = sp[0], y = sp[1];
  u16x8 o;
  o[0]=f2bf(x[0]); o[1]=f2bf(x[1]); o[2]=f2bf(x[2]); o[3]=f2bf(x[3]);
  o[4]=f2bf(y[0]); o[5]=f2bf(y[1]); o[6]=f2bf(y[2]); o[7]=f2bf(y[3]);
  *(u16x8*)(x0 + (size_t)m * 512 + kc) = o;
}

// ---------------- generic bf16 GEMM: C[M][N] = A[M][K] @ B[N][K]^T (+bias) ----------------
// 128x128 tile, BK=32, 4 waves each 64x64 (4x4 of 16x16x32 MFMA). m97-style staging.
__global__ __launch_bounds__(256) void gemm_bf16(const unsigned short* __restrict__ A,
                                                 const unsigned short* __restrict__ B,
                                                 float* __restrict__ C,
                                                 const float* __restrict__ bias,
                                                 int M, int N, int K) {
  __shared__ __align__(16) unsigned short As[128 * 32];
  __shared__ __align__(16) unsigned short Bs[128 * 32];
  const int tid = threadIdx.x;
  const int wave = tid >> 6, lane = tid & 63;
  const int lr = lane & 15, lk8 = (lane >> 4) * 8;
  const int wm = (wave >> 1) * 64, wn = (wave & 1) * 64;
  const size_t m0 = (size_t)blockIdx.y * 128;
  const size_t n0 = (size_t)blockIdx.x * 128;

  f32x4 acc[4][4];
#pragma unroll
  for (int i = 0; i < 4; ++i)
#pragma unroll
    for (int j = 0; j < 4; ++j) acc[i][j] = (f32x4){0.f, 0.f, 0.f, 0.f};

  const int c0 = tid, c1 = tid + 256;
  unsigned short* Asw = As + wave * 512;   // wave-uniform LDS base (bytes: wave*1024)
  unsigned short* Bsw = Bs + wave * 512;

  for (int kt = 0; kt < K; kt += 32) {
    __syncthreads();
    gll16(A + (m0 + (size_t)(c0 >> 2)) * K + kt + (c0 & 3) * 8, Asw);
    gll16(A + (m0 + (size_t)(c1 >> 2)) * K + kt + (c1 & 3) * 8, Asw + 2048);
    gll16(B + (n0 + (size_t)(c0 >> 2)) * K + kt + (c0 & 3) * 8, Bsw);
    gll16(B + (n0 + (size_t)(c1 >> 2)) * K + kt + (c1 & 3) * 8, Bsw + 2048);
    __syncthreads();
    bf16x8 a[4], b[4];
#pragma unroll
    for (int i = 0; i < 4; ++i) a[i] = *(const bf16x8*)&As[(wm + i * 16 + lr) * 32 + lk8];
#pragma unroll
    for (int j = 0; j < 4; ++j) b[j] = *(const bf16x8*)&Bs[(wn + j * 16 + lr) * 32 + lk8];
#pragma unroll
    for (int i = 0; i < 4; ++i)
#pragma unroll
      for (int j = 0; j < 4; ++j)
        acc[i][j] = __builtin_amdgcn_mfma_f32_16x16x32_bf16(a[i], b[j], acc[i][j], 0, 0, 0);
  }

  const int rq = (lane >> 4) * 4;
#pragma unroll
  for (int j = 0; j < 4; ++j) {
    const int col = (int)n0 + wn + j * 16 + lr;
    const float bv = bias ? bias[col] : 0.0f;
#pragma unroll
    for (int i = 0; i < 4; ++i) {
#pragma unroll
      for (int q = 0; q < 4; ++q) {
        const long m = (long)m0 + wm + i * 16 + rq + q;
        if (m < M) C[(size_t)m * N + col] = acc[i][j][q] + bv;
      }
    }
  }
}

// ---------------- grid barrier (hand-rolled, agent scope) ----------------
__device__ __forceinline__ void gbar(int* bar, int nb, int step) {
  __syncthreads();
  if (threadIdx.x == 0) {
    int old = __hip_atomic_fetch_add(&bar[0], 1, __ATOMIC_ACQ_REL, __HIP_MEMORY_SCOPE_AGENT);
    if (old == nb - 1) {
      __hip_atomic_store(&bar[0], 0, __ATOMIC_RELAXED, __HIP_MEMORY_SCOPE_AGENT);
      __hip_atomic_store(&bar[1], step + 1, __ATOMIC_RELEASE, __HIP_MEMORY_SCOPE_AGENT);
    } else {
      while (__hip_atomic_load(&bar[1], __ATOMIC_ACQUIRE, __HIP_MEMORY_SCOPE_AGENT) < step + 1) {
        __builtin_amdgcn_s_sleep(2);
      }
    }
  }
  __syncthreads();
}

// LDS XOR swizzle for 1024B-stride rows (kills 16-way ds_read_b128 conflicts)
__device__ __forceinline__ int swz(int row, int col8) {   // col8: element idx, mult of 8
  return row * 512 + ((((col8 >> 3) ^ (row & 7))) << 3);
}

// ---------------- LSTM recurrence (persistent, 32 blocks, 1 layer) ----------------
// block b owns hidden units [b*16, b*16+16); whh slice rows g*512+hid0+jj in LDS.
__global__ __launch_bounds__(256) void lstm_kernel(const unsigned short* __restrict__ whh,
                                                   const float* __restrict__ gin,   // [51*8][2048]
                                                   unsigned short* __restrict__ hb, // [2][16][512]
                                                   unsigned short* __restrict__ xout, // [512][512]
                                                   int* __restrict__ bar, int layer) {
  __shared__ __align__(16) unsigned short whh_s[64 * 512];
  __shared__ __align__(16) unsigned short h_s[16 * 512];
  __shared__ float gates_s[4][8][16];
  __shared__ float c_s[8][16];
  __shared__ float ht_s[8][16];

  const int tid = threadIdx.x;
  const int blk = blockIdx.x;
  const int hid0 = blk * 16;
  const int wave = tid >> 6, lane = tid & 63;
  const int lr = lane & 15, lk8 = (lane >> 4) * 8;

  // load whh slice: local row r = g*16+jj -> global row g*512+hid0+jj (swizzled store)
  for (int idx = tid; idx < 64 * 64; idx += 256) {
    int r = idx >> 6, cc = (idx & 63) * 8;
    int g = r >> 4, jj = r & 15;
    *(bf16x8*)&whh_s[swz(r, cc)] =
        *(const bf16x8*)&whh[((size_t)(g * 512 + hid0 + jj)) * 512 + cc];
  }
  if (tid < 128) c_s[tid >> 4][tid & 15] = 0.f;
  // zero our columns of both h ping-pong buffers (rows 8..15 stay 0 forever)
  for (int i = tid; i < 2 * 16 * 16; i += 256) {
    int b = i >> 8, r = (i >> 4) & 15, c = i & 15;
    hb[((size_t)b * 16 + r) * 512 + hid0 + c] = 0;
  }
  gbar(bar, 32, layer * 52);

  for (int t = 0; t < TO1; ++t) {
    // stage h (16 rows x 512, rows 8..15 are zeros) with swizzled LDS layout
    const unsigned short* hsrc = hb + (size_t)(t & 1) * 16 * 512;
    for (int idx = tid; idx < 16 * 64; idx += 256) {
      int r = idx >> 6, cc = (idx & 63) * 8;
      *(bf16x8*)&h_s[swz(r, cc)] = *(const bf16x8*)&hsrc[r * 512 + cc];
    }
    __syncthreads();
    // wave = gate g; compute (h @ whh_slice^T) for 16 hidden units, M=16(8 real)
    f32x4 acc = (f32x4){0.f, 0.f, 0.f, 0.f};
#pragma unroll
    for (int kk = 0; kk < 512; kk += 32) {
      bf16x8 a = *(const bf16x8*)&h_s[swz(lr, kk + lk8)];
      bf16x8 b = *(const bf16x8*)&whh_s[swz(wave * 16 + lr, kk + lk8)];
      acc = __builtin_amdgcn_mfma_f32_16x16x32_bf16(a, b, acc, 0, 0, 0);
    }
    {
      int nb4 = (lane >> 4) * 4;
#pragma unroll
      for (int q = 0; q < 4; ++q) {
        int n = nb4 + q;
        if (n < 8) {
          float v = acc[q] + gin[((size_t)t * 8 + n) * 2048 + wave * 512 + hid0 + lr];
          gates_s[wave][n][lr] = v;
        }
      }
    }
    __syncthreads();
    if (tid < 128) {
      int n = tid >> 4, jj = tid & 15;
      float gi = gates_s[0][n][jj], gf = gates_s[1][n][jj];
      float gg = gates_s[2][n][jj], go = gates_s[3][n][jj];
      float c = fast_sig(gf) * c_s[n][jj] + fast_sig(gi) * fast_tanh(gg);
      c_s[n][jj] = c;
      ht_s[n][jj] = fast_sig(go) * fast_tanh(c);
    }
    __syncthreads();
    if (tid < 64) {
      int n = tid >> 3, p = tid & 7;
      unsigned lo = f2bf(ht_s[n][2 * p]), hi = f2bf(ht_s[n][2 * p + 1]);
      unsigned pk = lo | (hi << 16);
      *((unsigned*)(hb + (size_t)((t + 1) & 1) * 16 * 512 + (size_t)n * 512 + hid0) + p) = pk;
      *((unsigned*)(xout + ((size_t)t * 8 + n) * 512 + hid0) + p) = pk;
    }
    gbar(bar, 32, layer * 52 + 1 + t);
  }
}

// ---------------- A = tanh(enc_p + dec_p) -> bf16 [81664][512] ----------------
__global__ __launch_bounds__(256) void tanha_kernel(const float* __restrict__ encp,
                                                    const float* __restrict__ decp,
                                                    unsigned short* __restrict__ Ab) {
  size_t idx = (size_t)blockIdx.x * 256 + threadIdx.x;
  int m = (int)(idx >> 6);
  int kc = ((int)idx & 63) * 8;
  if (m >= 81664) return;
  u16x8 o;
  if (m >= MJOINT) {
    o[0]=0;o[1]=0;o[2]=0;o[3]=0;o[4]=0;o[5]=0;o[6]=0;o[7]=0;
  } else {
    int n = m / (TIN * TO1);
    int rem = m - n * (TIN * TO1);
    int t = rem / TO1;
    int u = rem - t * TO1;
    const float4v* ep = (const float4v*)(encp + ((size_t)n * TIN + t) * 512 + kc);
    const float4v* dp = (const float4v*)(decp + ((size_t)u * 8 + n) * 512 + kc);
    float4v e0 = ep[0], e1 = ep[1], d0 = dp[0], d1 = dp[1];
    o[0]=f2bf(fast_tanh(e0[0]+d0[0])); o[1]=f2bf(fast_tanh(e0[1]+d0[1]));
    o[2]=f2bf(fast_tanh(e0[2]+d0[2])); o[3]=f2bf(fast_tanh(e0[3]+d0[3]));
    o[4]=f2bf(fast_tanh(e1[0]+d1[0])); o[5]=f2bf(fast_tanh(e1[1]+d1[1]));
    o[6]=f2bf(fast_tanh(e1[2]+d1[2])); o[7]=f2bf(fast_tanh(e1[3]+d1[3]));
  }
  *(u16x8*)(Ab + (size_t)m * 512 + kc) = o;
}

// ---------------- launch ----------------
extern "C" void kernel_launch(void* const* d_in, const int* in_sizes, int n_in,
                              void* d_out, int out_size, void* d_ws, size_t ws_size,
                              hipStream_t stream) {
  (void)in_sizes; (void)n_in; (void)out_size; (void)ws_size;
  const float* enc_out = (const float*)d_in[0];
  const int*   tgt     = (const int*)d_in[1];
  const float* embed   = (const float*)d_in[2];
  const float* w_ih    = (const float*)d_in[3];
  const float* w_hh    = (const float*)d_in[4];
  const float* b_ih    = (const float*)d_in[5];
  const float* b_hh    = (const float*)d_in[6];
  const float* enc_w   = (const float*)d_in[7];
  const float* dec_w   = (const float*)d_in[8];
  const float* dec_b   = (const float*)d_in[9];
  const float* out_w   = (const float*)d_in[10];

  char* ws = (char*)d_ws;
  unsigned short* enc_bf  = (unsigned short*)(ws + B_ENCBF);
  unsigned short* encw_bf = (unsigned short*)(ws + B_ENCW);
  unsigned short* decw_bf = (unsigned short*)(ws + B_DECW);
  unsigned short* outw_bf = (unsigned short*)(ws + B_OUTW);
  unsigned short* wih_bf  = (unsigned short*)(ws + B_WIH);
  unsigned short* whh_bf  = (unsigned short*)(ws + B_WHH);
  unsigned short* xs0     = (unsigned short*)(ws + B_X0);
  unsigned short* xs1     = (unsigned short*)(ws + B_X1);
  unsigned short* xs2     = (unsigned short*)(ws + B_X2);
  unsigned short* xs3     = (unsigned short*)(ws + B_X3);
  float* gin   = (float*)(ws + B_GIN);
  float* bsum  = (float*)(ws + B_BSUM);
  unsigned short* hbuf = (unsigned short*)(ws + B_HBUF);
  int*   bar   = (int*)(ws + B_BAR);
  float* encp  = (float*)(ws + B_ENCP);
  float* decp  = (float*)(ws + B_DECP);
  unsigned short* abuf = (unsigned short*)(ws + B_ABUF);
  float* Cout  = (float*)d_out;

  hipMemsetAsync(bar, 0, 16, stream);

  cvt_kernel<<<400, 256, 0, stream>>>(enc_out, enc_bf, 102400);   // 8*200*512/8
  cvt_kernel<<<128, 256, 0, stream>>>(enc_w, encw_bf, 32768);
  cvt_kernel<<<128, 256, 0, stream>>>(dec_w, decw_bf, 32768);
  cvt_kernel<<<256, 256, 0, stream>>>(out_w, outw_bf, 65536);
  cvt_kernel<<<1536, 256, 0, stream>>>(w_ih, wih_bf, 393216);
  cvt_kernel<<<1536, 256, 0, stream>>>(w_hh, whh_bf, 393216);
  bsum_kernel<<<24, 256, 0, stream>>>(b_ih, b_hh, bsum, 6144);
  embed_kernel<<<102, 256, 0, stream>>>(embed, tgt, xs0);

  unsigned short* xs[4] = {xs0, xs1, xs2, xs3};
  for (int l = 0; l < 3; ++l) {
    gemm_bf16<<<dim3(16, 4), 256, 0, stream>>>(
        xs[l], wih_bf + (size_t)l * 2048 * 512, gin, bsum + l * 2048, MROWS, 2048, 512);
    lstm_kernel<<<32, 256, 0, stream>>>(
        whh_bf + (size_t)l * 2048 * 512, gin, hbuf, xs[l + 1], bar, l);
  }

  gemm_bf16<<<dim3(4, 13), 256, 0, stream>>>(enc_bf, encw_bf, encp, nullptr, NB * TIN, 512, 512);
  gemm_bf16<<<dim3(4, 4), 256, 0, stream>>>(xs3, decw_bf, decp, dec_b, MROWS, 512, 512);
  tanha_kernel<<<20416, 256, 0, stream>>>(encp, decp, abuf);
  gemm_bf16<<<dim3(8, 638), 256, 0, stream>>>(abuf, outw_bf, Cout, nullptr, MJOINT, VSZ, 512);
}

// Round 2
// 997.888 us; speedup vs baseline: 1.2959x; 1.2959x over previous
//
#include <hip/hip_runtime.h>
#include <cstdint>
#include <cstddef>

typedef __attribute__((ext_vector_type(4))) float f32x4;
typedef __attribute__((ext_vector_type(8))) short bf16x8;      // MFMA operand (8 bf16)
typedef __attribute__((ext_vector_type(8))) unsigned short u16x8;
typedef __attribute__((ext_vector_type(4))) float float4v;

// ---- problem dims ----
#define NB   8
#define TIN  200
#define TO1  51
#define VSZ  1024
#define HSZ  512
static constexpr int MJOINT = NB * TIN * TO1;   // 81600
static constexpr int MROWS  = TO1 * NB;         // 408  (rows t*8+n)

// ---- ws layout (bytes) ----
static constexpr size_t B_ENCBF = 0;                           // 1664*512*2
static constexpr size_t B_ENCW  = B_ENCBF + 1664ull*512*2;     // 512*512*2
static constexpr size_t B_DECW  = B_ENCW  + 512ull*512*2;
static constexpr size_t B_OUTW  = B_DECW  + 512ull*512*2;      // 1024*512*2
static constexpr size_t B_WIH   = B_OUTW  + 1024ull*512*2;     // 3*2048*512*2
static constexpr size_t B_WHH   = B_WIH   + 3ull*2048*512*2;
static constexpr size_t B_XTR   = B_WHH   + 3ull*2048*512*2;   // 4*408*512*2 (x0,h1,h2,h3 traces)
static constexpr size_t B_ZROW  = B_XTR   + 4ull*408*512*2;    // 1024 (one zero row)
static constexpr size_t B_BSUM  = B_ZROW  + 1024;              // 3*2048*4
static constexpr size_t B_FLAGS = B_BSUM  + 3ull*2048*4;       // 512
static constexpr size_t B_ENCP  = B_FLAGS + 512;               // 1664*512*4
static constexpr size_t B_DECP  = B_ENCP  + 1664ull*512*4;     // 512*512*4
static constexpr size_t B_ABUF  = B_DECP  + 512ull*512*4;      // 81664*512*2

// ---- helpers ----
__device__ __forceinline__ unsigned short f2bf(float f) {
  union { float f; unsigned u; } v; v.f = f;
  unsigned r = v.u + 0x7FFFu + ((v.u >> 16) & 1u);
  return (unsigned short)(r >> 16);
}
__device__ __forceinline__ float fast_tanh(float x) {
  float t = __expf(2.0f * x);          // inf-safe: x>>0 -> 1, x<<0 -> -1
  return 1.0f - 2.0f / (t + 1.0f);
}
__device__ __forceinline__ float fast_sig(float x) {
  return 1.0f / (1.0f + __expf(-x));
}
__device__ __forceinline__ void gll16(const void* g, void* l) {
  __builtin_amdgcn_global_load_lds(
      (const __attribute__((address_space(1))) unsigned int*)g,
      (__attribute__((address_space(3))) unsigned int*)l, 16, 0, 0);
}
__device__ __forceinline__ void cvt8(const float* s, unsigned short* d) {
  const float4v* sp = (const float4v*)s;
  float4v x = sp[0], y = sp[1];
  u16x8 o;
  o[0]=f2bf(x[0]); o[1]=f2bf(x[1]); o[2]=f2bf(x[2]); o[3]=f2bf(x[3]);
  o[4]=f2bf(y[0]); o[5]=f2bf(y[1]); o[6]=f2bf(y[2]); o[7]=f2bf(y[3]);
  *(u16x8*)d = o;
}

// ---------------- fused fp32 -> bf16 convert for all weight/activation tensors ----------------
static constexpr int N_ENC  = 102400;           // 8*200*512/8
static constexpr int N_ENCW = 32768;
static constexpr int N_DECW = 32768;
static constexpr int N_OUTW = 65536;
static constexpr int N_WIH  = 393216;
static constexpr int N_WHH  = 393216;
static constexpr int P0 = N_ENC, P1 = P0+N_ENCW, P2 = P1+N_DECW, P3 = P2+N_OUTW,
                     P4 = P3+N_WIH, P5 = P4+N_WHH;   // 1019904 total (=3984*256)

__global__ __launch_bounds__(256) void cvt_all(const float* __restrict__ enc,
                                               const float* __restrict__ encw,
                                               const float* __restrict__ decw,
                                               const float* __restrict__ outw,
                                               const float* __restrict__ wih,
                                               const float* __restrict__ whh,
                                               unsigned short* __restrict__ d_enc,
                                               unsigned short* __restrict__ d_encw,
                                               unsigned short* __restrict__ d_decw,
                                               unsigned short* __restrict__ d_outw,
                                               unsigned short* __restrict__ d_wih,
                                               unsigned short* __restrict__ d_whh) {
  int i = blockIdx.x * 256 + threadIdx.x;
  const float* s; unsigned short* d; int rel;
  if      (i < P0) { s = enc;  d = d_enc;  rel = i; }
  else if (i < P1) { s = encw; d = d_encw; rel = i - P0; }
  else if (i < P2) { s = decw; d = d_decw; rel = i - P1; }
  else if (i < P3) { s = outw; d = d_outw; rel = i - P2; }
  else if (i < P4) { s = wih;  d = d_wih;  rel = i - P3; }
  else             { s = whh;  d = d_whh;  rel = i - P4; }
  cvt8(s + (size_t)rel * 8, d + (size_t)rel * 8);
}

// ---------------- bias sum: bsum = b_ih + b_hh ----------------
__global__ __launch_bounds__(256) void bsum_kernel(const float* __restrict__ a,
                                                   const float* __restrict__ b,
                                                   float* __restrict__ o, int n) {
  int i = blockIdx.x * 256 + threadIdx.x;
  if (i < n) o[i] = a[i] + b[i];
}

// ---------------- embedding gather -> bf16 xtr[0][t*8+n][512] ----------------
__global__ __launch_bounds__(256) void embed_kernel(const float* __restrict__ emb,
                                                    const int* __restrict__ tgt,
                                                    unsigned short* __restrict__ x0) {
  int idx = blockIdx.x * 256 + threadIdx.x;   // 408*64
  if (idx >= MROWS * 64) return;
  int m = idx >> 6, kc = (idx & 63) * 8;
  int t = m >> 3, n = m & 7;
  int v = tgt[n * TO1 + t];
  cvt8(emb + (size_t)v * 512 + kc, x0 + (size_t)m * 512 + kc);
}

// ---------------- generic bf16 GEMM: C[M][N] = A[M][K] @ B[N][K]^T (+bias) ----------------
// 128x128 tile, BK=32, 4 waves each 64x64 (4x4 of 16x16x32 MFMA). XCD-swizzled block order.
__global__ __launch_bounds__(256) void gemm_bf16(const unsigned short* __restrict__ A,
                                                 const unsigned short* __restrict__ B,
                                                 float* __restrict__ C,
                                                 const float* __restrict__ bias,
                                                 int M, int N, int K) {
  __shared__ __align__(16) unsigned short As[128 * 32];
  __shared__ __align__(16) unsigned short Bs[128 * 32];
  const int tid = threadIdx.x;
  const int wave = tid >> 6, lane = tid & 63;
  const int lr = lane & 15, lk8 = (lane >> 4) * 8;
  const int wm = (wave >> 1) * 64, wn = (wave & 1) * 64;

  // bijective XCD-aware remap (m204 form): each XCD gets a contiguous id chunk
  const int nwg = gridDim.x * gridDim.y;
  const int id = blockIdx.y * gridDim.x + blockIdx.x;
  const int q = nwg >> 3, r = nwg & 7, xcd = id & 7, rest = id >> 3;
  const int nid = (xcd < r ? xcd * (q + 1) : r * (q + 1) + (xcd - r) * q) + rest;
  const size_t n0 = (size_t)(nid % gridDim.x) * 128;
  const size_t m0 = (size_t)(nid / gridDim.x) * 128;

  f32x4 acc[4][4];
#pragma unroll
  for (int i = 0; i < 4; ++i)
#pragma unroll
    for (int j = 0; j < 4; ++j) acc[i][j] = (f32x4){0.f, 0.f, 0.f, 0.f};

  const int c0 = tid, c1 = tid + 256;
  unsigned short* Asw = As + wave * 512;   // wave-uniform LDS base
  unsigned short* Bsw = Bs + wave * 512;

  for (int kt = 0; kt < K; kt += 32) {
    __syncthreads();
    gll16(A + (m0 + (size_t)(c0 >> 2)) * K + kt + (c0 & 3) * 8, Asw);
    gll16(A + (m0 + (size_t)(c1 >> 2)) * K + kt + (c1 & 3) * 8, Asw + 2048);
    gll16(B + (n0 + (size_t)(c0 >> 2)) * K + kt + (c0 & 3) * 8, Bsw);
    gll16(B + (n0 + (size_t)(c1 >> 2)) * K + kt + (c1 & 3) * 8, Bsw + 2048);
    __syncthreads();
    bf16x8 a[4], b[4];
#pragma unroll
    for (int i = 0; i < 4; ++i) a[i] = *(const bf16x8*)&As[(wm + i * 16 + lr) * 32 + lk8];
#pragma unroll
    for (int j = 0; j < 4; ++j) b[j] = *(const bf16x8*)&Bs[(wn + j * 16 + lr) * 32 + lk8];
#pragma unroll
    for (int i = 0; i < 4; ++i)
#pragma unroll
      for (int j = 0; j < 4; ++j)
        acc[i][j] = __builtin_amdgcn_mfma_f32_16x16x32_bf16(a[i], b[j], acc[i][j], 0, 0, 0);
  }

  const int rq = (lane >> 4) * 4;
#pragma unroll
  for (int j = 0; j < 4; ++j) {
    const int col = (int)n0 + wn + j * 16 + lr;
    const float bv = bias ? bias[col] : 0.0f;
#pragma unroll
    for (int i = 0; i < 4; ++i) {
#pragma unroll
      for (int q2 = 0; q2 < 4; ++q2) {
        const long m = (long)m0 + wm + i * 16 + rq + q2;
        if (m < M) C[(size_t)m * N + col] = acc[i][j][q2] + bv;
      }
    }
  }
}

// ---------------- fused 3-layer LSTM, persistent, pipelined via per-block flags ----------------
// 96 blocks: layer l = blk/32 (32 blocks each owning 16 hidden units x 4 gates).
// W slice ([wih|whh] rows) lives in VGPRs (128/lane). Per step: poll flags, A from global,
// 32 MFMA (16x16x32), nonlinearity, pack h -> xtr[l+1], release flag.
__global__ __launch_bounds__(256) void rnn_kernel(const unsigned short* __restrict__ wih,
                                                  const unsigned short* __restrict__ whh,
                                                  const float* __restrict__ bsum,
                                                  unsigned short* __restrict__ xtr,
                                                  const unsigned short* __restrict__ zrow,
                                                  int* __restrict__ flags) {
  const int tid = threadIdx.x;
  const int l = blockIdx.x >> 5;
  const int blk = blockIdx.x & 31;
  const int hid0 = blk << 4;
  const int wave = tid >> 6, lane = tid & 63;
  const int lr = lane & 15, lk8 = (lane >> 4) << 3;

  // --- persistent weight fragments: w[s], s<16 -> wih (k=s*32+lk8), s>=16 -> whh ---
  bf16x8 w[32];
  {
    const size_t rowbase = ((size_t)l * 2048 + (size_t)wave * 512 + hid0 + lr) * 512;
#pragma unroll
    for (int s = 0; s < 16; ++s) w[s] = *(const bf16x8*)&wih[rowbase + s * 32 + lk8];
#pragma unroll
    for (int s = 0; s < 16; ++s) w[16 + s] = *(const bf16x8*)&whh[rowbase + s * 32 + lk8];
  }
  const float bias = bsum[(size_t)l * 2048 + (size_t)wave * 512 + hid0 + lr];

  __shared__ float gates_s[4][8][16];
  __shared__ float c_s[8][16];
  __shared__ float ht_s[8][16];
  if (tid < 128) c_s[tid >> 4][tid & 15] = 0.f;
  __syncthreads();

  const unsigned short* xin = xtr + (size_t)l * MROWS * 512;
  unsigned short* xout = xtr + (size_t)(l + 1) * MROWS * 512;
  const int r8 = lr & 7;

  for (int t = 0; t < TO1; ++t) {
    // ---- phase 1: x-dependency (layer l-1 step t done) ----
    if (l > 0) {
      const int idx = (l - 1) * 32 + (lane & 31);
      const int need = t + 1;
      for (;;) {
        int v = __hip_atomic_load(&flags[idx], __ATOMIC_ACQUIRE, __HIP_MEMORY_SCOPE_AGENT);
        if (__all(v >= need)) break;
        __builtin_amdgcn_s_sleep(1);
      }
      __builtin_amdgcn_fence(__ATOMIC_ACQUIRE, "agent");
    }
    const unsigned short* xrow = xin + ((size_t)t * 8 + r8) * 512;
    const unsigned short* hrow = (t == 0) ? zrow : xout + ((size_t)(t - 1) * 8 + r8) * 512;

    f32x4 acc0 = (f32x4){0.f, 0.f, 0.f, 0.f};
    f32x4 acc1 = (f32x4){0.f, 0.f, 0.f, 0.f};
    bf16x8 a[2][4];

    // ---- x half: chunks 0..3 (s = 0..15) ----
#pragma unroll
    for (int j = 0; j < 4; ++j) a[0][j] = *(const bf16x8*)&xrow[j * 32 + lk8];
#pragma unroll
    for (int c = 0; c < 4; ++c) {
      if (c < 3) {
#pragma unroll
        for (int j = 0; j < 4; ++j)
          a[(c + 1) & 1][j] = *(const bf16x8*)&xrow[((c + 1) * 4 + j) * 32 + lk8];
      }
      f32x4& ac = (c & 1) ? acc1 : acc0;
#pragma unroll
      for (int j = 0; j < 4; ++j)
        ac = __builtin_amdgcn_mfma_f32_16x16x32_bf16(a[c & 1][j], w[c * 4 + j], ac, 0, 0, 0);
    }

    // ---- phase 2: h-dependency (own layer step t-1 done by all 32 blocks) ----
    if (t > 0) {
      const int idx = l * 32 + (lane & 31);
      for (;;) {
        int v = __hip_atomic_load(&flags[idx], __ATOMIC_ACQUIRE, __HIP_MEMORY_SCOPE_AGENT);
        if (__all(v >= t)) break;
        __builtin_amdgcn_s_sleep(1);
      }
      __builtin_amdgcn_fence(__ATOMIC_ACQUIRE, "agent");
    }

    // ---- h half: chunks 4..7 (s = 16..31) ----
#pragma unroll
    for (int j = 0; j < 4; ++j) a[0][j] = *(const bf16x8*)&hrow[j * 32 + lk8];
#pragma unroll
    for (int c = 4; c < 8; ++c) {
      if (c < 7) {
#pragma unroll
        for (int j = 0; j < 4; ++j)
          a[(c + 1) & 1][j] = *(const bf16x8*)&hrow[((c - 3) * 4 + j) * 32 + lk8];
      }
      f32x4& ac = (c & 1) ? acc1 : acc0;
#pragma unroll
      for (int j = 0; j < 4; ++j)
        ac = __builtin_amdgcn_mfma_f32_16x16x32_bf16(a[c & 1][j], w[c * 4 + j], ac, 0, 0, 0);
    }

    // ---- gates -> LDS (rows 8..15 are batch padding, discarded) ----
    {
      const int rq = (lane >> 4) * 4;
      f32x4 g = acc0 + acc1;
#pragma unroll
      for (int q2 = 0; q2 < 4; ++q2) {
        int n = rq + q2;
        if (n < 8) gates_s[wave][n][lr] = g[q2] + bias;
      }
    }
    __syncthreads();
    if (tid < 128) {
      int n = tid >> 4, jj = tid & 15;
      float gi = gates_s[0][n][jj], gf = gates_s[1][n][jj];
      float gg = gates_s[2][n][jj], go = gates_s[3][n][jj];
      float c = fast_sig(gf) * c_s[n][jj] + fast_sig(gi) * fast_tanh(gg);
      c_s[n][jj] = c;
      ht_s[n][jj] = fast_sig(go) * fast_tanh(c);
    }
    __syncthreads();
    if (tid < 64) {
      int n = tid >> 3, p = tid & 7;
      unsigned lo = f2bf(ht_s[n][2 * p]), hi = f2bf(ht_s[n][2 * p + 1]);
      *((unsigned*)(xout + ((size_t)t * 8 + n) * 512 + hid0) + p) = lo | (hi << 16);
    }
    if (tid == 0)
      __hip_atomic_store(&flags[l * 32 + blk], t + 1, __ATOMIC_RELEASE, __HIP_MEMORY_SCOPE_AGENT);
  }
}

// ---------------- A = tanh(enc_p + dec_p) -> bf16 [81664][512] ----------------
__global__ __launch_bounds__(256) void tanha_kernel(const float* __restrict__ encp,
                                                    const float* __restrict__ decp,
                                                    unsigned short* __restrict__ Ab) {
  size_t idx = (size_t)blockIdx.x * 256 + threadIdx.x;
  int m = (int)(idx >> 6);
  int kc = ((int)idx & 63) * 8;
  if (m >= 81664) return;
  u16x8 o;
  if (m >= MJOINT) {
    o[0]=0;o[1]=0;o[2]=0;o[3]=0;o[4]=0;o[5]=0;o[6]=0;o[7]=0;
  } else {
    int n = m / (TIN * TO1);
    int rem = m - n * (TIN * TO1);
    int t = rem / TO1;
    int u = rem - t * TO1;
    const float4v* ep = (const float4v*)(encp + ((size_t)n * TIN + t) * 512 + kc);
    const float4v* dp = (const float4v*)(decp + ((size_t)u * 8 + n) * 512 + kc);
    float4v e0 = ep[0], e1 = ep[1], d0 = dp[0], d1 = dp[1];
    o[0]=f2bf(fast_tanh(e0[0]+d0[0])); o[1]=f2bf(fast_tanh(e0[1]+d0[1]));
    o[2]=f2bf(fast_tanh(e0[2]+d0[2])); o[3]=f2bf(fast_tanh(e0[3]+d0[3]));
    o[4]=f2bf(fast_tanh(e1[0]+d1[0])); o[5]=f2bf(fast_tanh(e1[1]+d1[1]));
    o[6]=f2bf(fast_tanh(e1[2]+d1[2])); o[7]=f2bf(fast_tanh(e1[3]+d1[3]));
  }
  *(u16x8*)(Ab + (size_t)m * 512 + kc) = o;
}

// ---------------- launch ----------------
extern "C" void kernel_launch(void* const* d_in, const int* in_sizes, int n_in,
                              void* d_out, int out_size, void* d_ws, size_t ws_size,
                              hipStream_t stream) {
  (void)in_sizes; (void)n_in; (void)out_size; (void)ws_size;
  const float* enc_out = (const float*)d_in[0];
  const int*   tgt     = (const int*)d_in[1];
  const float* embed   = (const float*)d_in[2];
  const float* w_ih    = (const float*)d_in[3];
  const float* w_hh    = (const float*)d_in[4];
  const float* b_ih    = (const float*)d_in[5];
  const float* b_hh    = (const float*)d_in[6];
  const float* enc_w   = (const float*)d_in[7];
  const float* dec_w   = (const float*)d_in[8];
  const float* dec_b   = (const float*)d_in[9];
  const float* out_w   = (const float*)d_in[10];

  char* ws = (char*)d_ws;
  unsigned short* enc_bf  = (unsigned short*)(ws + B_ENCBF);
  unsigned short* encw_bf = (unsigned short*)(ws + B_ENCW);
  unsigned short* decw_bf = (unsigned short*)(ws + B_DECW);
  unsigned short* outw_bf = (unsigned short*)(ws + B_OUTW);
  unsigned short* wih_bf  = (unsigned short*)(ws + B_WIH);
  unsigned short* whh_bf  = (unsigned short*)(ws + B_WHH);
  unsigned short* xtr     = (unsigned short*)(ws + B_XTR);
  unsigned short* zrow    = (unsigned short*)(ws + B_ZROW);
  float* bsum  = (float*)(ws + B_BSUM);
  int*   flags = (int*)(ws + B_FLAGS);
  float* encp  = (float*)(ws + B_ENCP);
  float* decp  = (float*)(ws + B_DECP);
  unsigned short* abuf = (unsigned short*)(ws + B_ABUF);
  float* Cout  = (float*)d_out;

  hipMemsetAsync(flags, 0, 512, stream);
  hipMemsetAsync(zrow, 0, 1024, stream);

  cvt_all<<<3984, 256, 0, stream>>>(enc_out, enc_w, dec_w, out_w, w_ih, w_hh,
                                    enc_bf, encw_bf, decw_bf, outw_bf, wih_bf, whh_bf);
  bsum_kernel<<<24, 256, 0, stream>>>(b_ih, b_hh, bsum, 6144);
  embed_kernel<<<102, 256, 0, stream>>>(embed, tgt, xtr);

  rnn_kernel<<<96, 256, 0, stream>>>(wih_bf, whh_bf, bsum, xtr, zrow, flags);

  gemm_bf16<<<dim3(4, 13), 256, 0, stream>>>(enc_bf, encw_bf, encp, nullptr, NB * TIN, 512, 512);
  gemm_bf16<<<dim3(4, 4), 256, 0, stream>>>(xtr + 3ull * MROWS * 512, decw_bf, decp, dec_b,
                                            MROWS, 512, 512);
  tanha_kernel<<<20416, 256, 0, stream>>>(encp, decp, abuf);
  gemm_bf16<<<dim3(8, 638), 256, 0, stream>>>(abuf, outw_bf, Cout, nullptr, MJOINT, VSZ, 512);
}

// Round 3
// 935.197 us; speedup vs baseline: 1.3828x; 1.0670x over previous
//
#include <hip/hip_runtime.h>
#include <cstdint>
#include <cstddef>

typedef __attribute__((ext_vector_type(4))) float f32x4;
typedef __attribute__((ext_vector_type(8))) short bf16x8;      // MFMA operand (8 bf16)
typedef __attribute__((ext_vector_type(8))) unsigned short u16x8;
typedef __attribute__((ext_vector_type(4))) float float4v;

// ---- problem dims ----
#define NB   8
#define TIN  200
#define TO1  51
#define VSZ  1024
#define HSZ  512
static constexpr int MJOINT = NB * TIN * TO1;   // 81600
static constexpr int MROWS  = TO1 * NB;         // 408  (rows t*8+n)

// ---- ws layout (bytes) ----
static constexpr size_t B_ENCBF = 0;                           // 1664*512*2
static constexpr size_t B_ENCW  = B_ENCBF + 1664ull*512*2;     // 512*512*2
static constexpr size_t B_DECW  = B_ENCW  + 512ull*512*2;
static constexpr size_t B_OUTW  = B_DECW  + 512ull*512*2;      // 1024*512*2
static constexpr size_t B_WIH   = B_OUTW  + 1024ull*512*2;     // 3*2048*512*2
static constexpr size_t B_WHH   = B_WIH   + 3ull*2048*512*2;
static constexpr size_t B_XTR   = B_WHH   + 3ull*2048*512*2;   // 4*408*512*2 (x0,h1,h2,h3 traces)
static constexpr size_t B_BSUM  = B_XTR   + 4ull*408*512*2;    // 3*2048*4
static constexpr size_t B_FLAGS = B_BSUM  + 3ull*2048*4;       // 512
static constexpr size_t B_ENCP  = B_FLAGS + 512;               // 1664*512*4
static constexpr size_t B_DECP  = B_ENCP  + 1664ull*512*4;     // 512*512*4
static constexpr size_t B_ABUF  = B_DECP  + 512ull*512*4;      // 81664*512*2

// ---- helpers ----
__device__ __forceinline__ unsigned short f2bf(float f) {
  union { float f; unsigned u; } v; v.f = f;
  unsigned r = v.u + 0x7FFFu + ((v.u >> 16) & 1u);
  return (unsigned short)(r >> 16);
}
__device__ __forceinline__ float fast_tanh(float x) {
  float t = __expf(2.0f * x);          // inf-safe: x>>0 -> 1, x<<0 -> -1
  return 1.0f - 2.0f / (t + 1.0f);
}
__device__ __forceinline__ float fast_sig(float x) {
  return 1.0f / (1.0f + __expf(-x));
}
__device__ __forceinline__ void gll16(const void* g, void* l) {
  __builtin_amdgcn_global_load_lds(
      (const __attribute__((address_space(1))) unsigned int*)g,
      (__attribute__((address_space(3))) unsigned int*)l, 16, 0, 0);
}
__device__ __forceinline__ void cvt8(const float* s, unsigned short* d) {
  const float4v* sp = (const float4v*)s;
  float4v x = sp[0], y = sp[1];
  u16x8 o;
  o[0]=f2bf(x[0]); o[1]=f2bf(x[1]); o[2]=f2bf(x[2]); o[3]=f2bf(x[3]);
  o[4]=f2bf(y[0]); o[5]=f2bf(y[1]); o[6]=f2bf(y[2]); o[7]=f2bf(y[3]);
  *(u16x8*)d = o;
}

// ---------------- fused fp32 -> bf16 convert for all weight/activation tensors ----------------
static constexpr int N_ENC  = 102400;           // 8*200*512/8
static constexpr int N_ENCW = 32768;
static constexpr int N_DECW = 32768;
static constexpr int N_OUTW = 65536;
static constexpr int N_WIH  = 393216;
static constexpr int N_WHH  = 393216;
static constexpr int P0 = N_ENC, P1 = P0+N_ENCW, P2 = P1+N_DECW, P3 = P2+N_OUTW,
                     P4 = P3+N_WIH;   // total 1019904 (=3984*256)

__global__ __launch_bounds__(256) void cvt_all(const float* __restrict__ enc,
                                               const float* __restrict__ encw,
                                               const float* __restrict__ decw,
                                               const float* __restrict__ outw,
                                               const float* __restrict__ wih,
                                               const float* __restrict__ whh,
                                               unsigned short* __restrict__ d_enc,
                                               unsigned short* __restrict__ d_encw,
                                               unsigned short* __restrict__ d_decw,
                                               unsigned short* __restrict__ d_outw,
                                               unsigned short* __restrict__ d_wih,
                                               unsigned short* __restrict__ d_whh) {
  int i = blockIdx.x * 256 + threadIdx.x;
  const float* s; unsigned short* d; int rel;
  if      (i < P0) { s = enc;  d = d_enc;  rel = i; }
  else if (i < P1) { s = encw; d = d_encw; rel = i - P0; }
  else if (i < P2) { s = decw; d = d_decw; rel = i - P1; }
  else if (i < P3) { s = outw; d = d_outw; rel = i - P2; }
  else if (i < P4) { s = wih;  d = d_wih;  rel = i - P3; }
  else             { s = whh;  d = d_whh;  rel = i - P4; }
  cvt8(s + (size_t)rel * 8, d + (size_t)rel * 8);
}

// ---------------- bias sum: bsum = b_ih + b_hh ----------------
__global__ __launch_bounds__(256) void bsum_kernel(const float* __restrict__ a,
                                                   const float* __restrict__ b,
                                                   float* __restrict__ o, int n) {
  int i = blockIdx.x * 256 + threadIdx.x;
  if (i < n) o[i] = a[i] + b[i];
}

// ---------------- embedding gather -> bf16 xtr[0][t*8+n][512] ----------------
__global__ __launch_bounds__(256) void embed_kernel(const float* __restrict__ emb,
                                                    const int* __restrict__ tgt,
                                                    unsigned short* __restrict__ x0) {
  int idx = blockIdx.x * 256 + threadIdx.x;   // 408*64
  if (idx >= MROWS * 64) return;
  int m = idx >> 6, kc = (idx & 63) * 8;
  int t = m >> 3, n = m & 7;
  int v = tgt[n * TO1 + t];
  cvt8(emb + (size_t)v * 512 + kc, x0 + (size_t)m * 512 + kc);
}

// ---------------- generic bf16 GEMM: C[M][N] = A[M][K] @ B[N][K]^T (+bias) ----------------
// 128x128 tile, BK=32, 4 waves each 64x64 (4x4 of 16x16x32 MFMA). XCD-swizzled block order.
__global__ __launch_bounds__(256) void gemm_bf16(const unsigned short* __restrict__ A,
                                                 const unsigned short* __restrict__ B,
                                                 float* __restrict__ C,
                                                 const float* __restrict__ bias,
                                                 int M, int N, int K) {
  __shared__ __align__(16) unsigned short As[128 * 32];
  __shared__ __align__(16) unsigned short Bs[128 * 32];
  const int tid = threadIdx.x;
  const int wave = tid >> 6, lane = tid & 63;
  const int lr = lane & 15, lk8 = (lane >> 4) * 8;
  const int wm = (wave >> 1) * 64, wn = (wave & 1) * 64;

  // bijective XCD-aware remap (m204 form): each XCD gets a contiguous id chunk
  const int nwg = gridDim.x * gridDim.y;
  const int id = blockIdx.y * gridDim.x + blockIdx.x;
  const int q = nwg >> 3, r = nwg & 7, xcd = id & 7, rest = id >> 3;
  const int nid = (xcd < r ? xcd * (q + 1) : r * (q + 1) + (xcd - r) * q) + rest;
  const size_t n0 = (size_t)(nid % gridDim.x) * 128;
  const size_t m0 = (size_t)(nid / gridDim.x) * 128;

  f32x4 acc[4][4];
#pragma unroll
  for (int i = 0; i < 4; ++i)
#pragma unroll
    for (int j = 0; j < 4; ++j) acc[i][j] = (f32x4){0.f, 0.f, 0.f, 0.f};

  const int c0 = tid, c1 = tid + 256;
  unsigned short* Asw = As + wave * 512;   // wave-uniform LDS base
  unsigned short* Bsw = Bs + wave * 512;

  for (int kt = 0; kt < K; kt += 32) {
    __syncthreads();
    gll16(A + (m0 + (size_t)(c0 >> 2)) * K + kt + (c0 & 3) * 8, Asw);
    gll16(A + (m0 + (size_t)(c1 >> 2)) * K + kt + (c1 & 3) * 8, Asw + 2048);
    gll16(B + (n0 + (size_t)(c0 >> 2)) * K + kt + (c0 & 3) * 8, Bsw);
    gll16(B + (n0 + (size_t)(c1 >> 2)) * K + kt + (c1 & 3) * 8, Bsw + 2048);
    __syncthreads();
    bf16x8 a[4], b[4];
#pragma unroll
    for (int i = 0; i < 4; ++i) a[i] = *(const bf16x8*)&As[(wm + i * 16 + lr) * 32 + lk8];
#pragma unroll
    for (int j = 0; j < 4; ++j) b[j] = *(const bf16x8*)&Bs[(wn + j * 16 + lr) * 32 + lk8];
#pragma unroll
    for (int i = 0; i < 4; ++i)
#pragma unroll
      for (int j = 0; j < 4; ++j)
        acc[i][j] = __builtin_amdgcn_mfma_f32_16x16x32_bf16(a[i], b[j], acc[i][j], 0, 0, 0);
  }

  const int rq = (lane >> 4) * 4;
#pragma unroll
  for (int j = 0; j < 4; ++j) {
    const int col = (int)n0 + wn + j * 16 + lr;
    const float bv = bias ? bias[col] : 0.0f;
#pragma unroll
    for (int i = 0; i < 4; ++i) {
#pragma unroll
      for (int q2 = 0; q2 < 4; ++q2) {
        const long m = (long)m0 + wm + i * 16 + rq + q2;
        if (m < M) C[(size_t)m * N + col] = acc[i][j][q2] + bv;
      }
    }
  }
}

// ---------------- fused 3-layer LSTM, persistent, pipelined via per-block flags ----------------
// 48 blocks x 512 threads: layer l = blk/16; block owns 32 hidden units (hid0 = (blk%16)*32).
// wave w: gate g = w>>1, hidden half hh = (w&1)*16; 16 gate rows x K=1024 in 128 pinned VGPRs.
// Per step: wave0 polls per-block flags (release-stores, no RMW), syncthreads, 16/32 MFMAs,
// nonlinearity (c in regs of tid<256), pack h -> xtr[l+1], release flag.
__global__ __launch_bounds__(512) void rnn_kernel(const unsigned short* __restrict__ wih,
                                                  const unsigned short* __restrict__ whh,
                                                  const float* __restrict__ bsum,
                                                  unsigned short* __restrict__ xtr,
                                                  int* __restrict__ flags) {
  const int tid = threadIdx.x;
  const int l = blockIdx.x >> 4;
  const int b16 = blockIdx.x & 15;
  const int hid0 = b16 << 5;
  const int wave = tid >> 6, lane = tid & 63;
  const int lr = lane & 15, lk8 = (lane >> 4) << 3;
  const int g = wave >> 1, hh = (wave & 1) << 4;

  // --- persistent weight fragments, pinned in VGPRs (asm-defined so fences can't respill) ---
  bf16x8 w[32];
  {
    const size_t rowbase = ((size_t)l * 2048 + (size_t)g * 512 + hid0 + hh + lr) * 512;
#pragma unroll
    for (int s = 0; s < 16; ++s) w[s] = *(const bf16x8*)&wih[rowbase + s * 32 + lk8];
#pragma unroll
    for (int s = 0; s < 16; ++s) w[16 + s] = *(const bf16x8*)&whh[rowbase + s * 32 + lk8];
#pragma unroll
    for (int s = 0; s < 32; ++s) asm volatile("" : "+v"(w[s]));
  }
  float bias = bsum[(size_t)l * 2048 + (size_t)g * 512 + hid0 + hh + lr];

  __shared__ float gates_s[4][8][32];

  const unsigned short* xin = xtr + (size_t)l * MROWS * 512;
  unsigned short* xout = xtr + (size_t)(l + 1) * MROWS * 512;
  const int r8 = lr & 7;
  float c_reg = 0.f;   // cell state, lives in regs of tid<256

  for (int t = 0; t < TO1; ++t) {
    // ---- dependency wait: wave0 polls, everyone else parks at the barrier ----
    if (l > 0 || t > 0) {
      if (wave == 0) {
        const bool active = (lane < 16) ? (l > 0) : (lane < 32 && t > 0);
        const int fidx = (lane < 16) ? ((l - 1) * 32 + lane) : (l * 32 + (lane & 15));
        const int need = (lane < 16) ? (t + 1) : t;
        for (;;) {
          bool ok = true;
          if (active) {
            int v = __hip_atomic_load(&flags[fidx], __ATOMIC_RELAXED, __HIP_MEMORY_SCOPE_AGENT);
            ok = (v >= need);
          }
          if (__all(ok)) break;
          __builtin_amdgcn_s_sleep(2);
        }
      }
      __syncthreads();
      __builtin_amdgcn_fence(__ATOMIC_ACQUIRE, "agent");
    }

    const unsigned short* xrow = xin + ((size_t)t * 8 + r8) * 512;
    const unsigned short* hrow = xout + ((size_t)(t - 1) * 8 + r8) * 512;  // valid t>0

    f32x4 acc0 = (f32x4){0.f, 0.f, 0.f, 0.f};
    f32x4 acc1 = (f32x4){0.f, 0.f, 0.f, 0.f};
    bf16x8 a[2][4];

    // ---- x half: chunks 0..3 (w[0..15]) ----
#pragma unroll
    for (int j = 0; j < 4; ++j) a[0][j] = *(const bf16x8*)&xrow[j * 32 + lk8];
#pragma unroll
    for (int c = 0; c < 4; ++c) {
      if (c < 3) {
#pragma unroll
        for (int j = 0; j < 4; ++j)
          a[(c + 1) & 1][j] = *(const bf16x8*)&xrow[((c + 1) * 4 + j) * 32 + lk8];
      } else if (t > 0) {
#pragma unroll
        for (int j = 0; j < 4; ++j) a[0][j] = *(const bf16x8*)&hrow[j * 32 + lk8];
      }
      f32x4& ac = (c & 1) ? acc1 : acc0;
#pragma unroll
      for (int j = 0; j < 4; ++j)
        ac = __builtin_amdgcn_mfma_f32_16x16x32_bf16(a[c & 1][j], w[c * 4 + j], ac, 0, 0, 0);
    }
    // ---- h half: chunks 4..7 (w[16..31]); h==0 at t==0, skip entirely ----
    if (t > 0) {
#pragma unroll
      for (int c = 4; c < 8; ++c) {
        if (c < 7) {
#pragma unroll
          for (int j = 0; j < 4; ++j)
            a[(c + 1) & 1][j] = *(const bf16x8*)&hrow[((c - 3) * 4 + j) * 32 + lk8];
        }
        f32x4& ac = (c & 1) ? acc1 : acc0;
#pragma unroll
        for (int j = 0; j < 4; ++j)
          ac = __builtin_amdgcn_mfma_f32_16x16x32_bf16(a[c & 1][j], w[16 + (c - 4) * 4 + j], ac, 0, 0, 0);
      }
    }

    // ---- gates -> LDS (acc rows 8..15 are batch padding, discarded) ----
    {
      const int rq = (lane >> 4) * 4;
      f32x4 gsum = acc0 + acc1;
#pragma unroll
      for (int q2 = 0; q2 < 4; ++q2) {
        int n = rq + q2;
        if (n < 8) gates_s[g][n][hh + lr] = gsum[q2] + bias;
      }
    }
    __syncthreads();
    if (tid < 256) {
      int n = tid >> 5, jj = tid & 31;
      float gi = gates_s[0][n][jj], gf = gates_s[1][n][jj];
      float gg = gates_s[2][n][jj], go = gates_s[3][n][jj];
      c_reg = fast_sig(gf) * c_reg + fast_sig(gi) * fast_tanh(gg);
      float ht = fast_sig(go) * fast_tanh(c_reg);
      float htn = __shfl_down(ht, 1);
      if (!(jj & 1)) {
        unsigned pk = (unsigned)f2bf(ht) | ((unsigned)f2bf(htn) << 16);
        *(unsigned*)(xout + ((size_t)t * 8 + n) * 512 + hid0 + jj) = pk;
      }
    }
    __syncthreads();   // all h stores drained (barrier waits vmcnt) before flag release
    if (tid == 0) {
      __builtin_amdgcn_fence(__ATOMIC_RELEASE, "agent");
      __hip_atomic_store(&flags[l * 32 + b16], t + 1, __ATOMIC_RELAXED, __HIP_MEMORY_SCOPE_AGENT);
    }
  }
}

// ---------------- A = tanh(enc_p + dec_p) -> bf16 [81664][512] ----------------
__global__ __launch_bounds__(256) void tanha_kernel(const float* __restrict__ encp,
                                                    const float* __restrict__ decp,
                                                    unsigned short* __restrict__ Ab) {
  size_t idx = (size_t)blockIdx.x * 256 + threadIdx.x;
  int m = (int)(idx >> 6);
  int kc = ((int)idx & 63) * 8;
  if (m >= 81664) return;
  u16x8 o;
  if (m >= MJOINT) {
    o[0]=0;o[1]=0;o[2]=0;o[3]=0;o[4]=0;o[5]=0;o[6]=0;o[7]=0;
  } else {
    int n = m / (TIN * TO1);
    int rem = m - n * (TIN * TO1);
    int t = rem / TO1;
    int u = rem - t * TO1;
    const float4v* ep = (const float4v*)(encp + ((size_t)n * TIN + t) * 512 + kc);
    const float4v* dp = (const float4v*)(decp + ((size_t)u * 8 + n) * 512 + kc);
    float4v e0 = ep[0], e1 = ep[1], d0 = dp[0], d1 = dp[1];
    o[0]=f2bf(fast_tanh(e0[0]+d0[0])); o[1]=f2bf(fast_tanh(e0[1]+d0[1]));
    o[2]=f2bf(fast_tanh(e0[2]+d0[2])); o[3]=f2bf(fast_tanh(e0[3]+d0[3]));
    o[4]=f2bf(fast_tanh(e1[0]+d1[0])); o[5]=f2bf(fast_tanh(e1[1]+d1[1]));
    o[6]=f2bf(fast_tanh(e1[2]+d1[2])); o[7]=f2bf(fast_tanh(e1[3]+d1[3]));
  }
  *(u16x8*)(Ab + (size_t)m * 512 + kc) = o;
}

// ---------------- launch ----------------
extern "C" void kernel_launch(void* const* d_in, const int* in_sizes, int n_in,
                              void* d_out, int out_size, void* d_ws, size_t ws_size,
                              hipStream_t stream) {
  (void)in_sizes; (void)n_in; (void)out_size; (void)ws_size;
  const float* enc_out = (const float*)d_in[0];
  const int*   tgt     = (const int*)d_in[1];
  const float* embed   = (const float*)d_in[2];
  const float* w_ih    = (const float*)d_in[3];
  const float* w_hh    = (const float*)d_in[4];
  const float* b_ih    = (const float*)d_in[5];
  const float* b_hh    = (const float*)d_in[6];
  const float* enc_w   = (const float*)d_in[7];
  const float* dec_w   = (const float*)d_in[8];
  const float* dec_b   = (const float*)d_in[9];
  const float* out_w   = (const float*)d_in[10];

  char* ws = (char*)d_ws;
  unsigned short* enc_bf  = (unsigned short*)(ws + B_ENCBF);
  unsigned short* encw_bf = (unsigned short*)(ws + B_ENCW);
  unsigned short* decw_bf = (unsigned short*)(ws + B_DECW);
  unsigned short* outw_bf = (unsigned short*)(ws + B_OUTW);
  unsigned short* wih_bf  = (unsigned short*)(ws + B_WIH);
  unsigned short* whh_bf  = (unsigned short*)(ws + B_WHH);
  unsigned short* xtr     = (unsigned short*)(ws + B_XTR);
  float* bsum  = (float*)(ws + B_BSUM);
  int*   flags = (int*)(ws + B_FLAGS);
  float* encp  = (float*)(ws + B_ENCP);
  float* decp  = (float*)(ws + B_DECP);
  unsigned short* abuf = (unsigned short*)(ws + B_ABUF);
  float* Cout  = (float*)d_out;

  hipMemsetAsync(flags, 0, 512, stream);

  cvt_all<<<3984, 256, 0, stream>>>(enc_out, enc_w, dec_w, out_w, w_ih, w_hh,
                                    enc_bf, encw_bf, decw_bf, outw_bf, wih_bf, whh_bf);
  bsum_kernel<<<24, 256, 0, stream>>>(b_ih, b_hh, bsum, 6144);
  embed_kernel<<<102, 256, 0, stream>>>(embed, tgt, xtr);

  rnn_kernel<<<48, 512, 0, stream>>>(wih_bf, whh_bf, bsum, xtr, flags);

  gemm_bf16<<<dim3(4, 13), 256, 0, stream>>>(enc_bf, encw_bf, encp, nullptr, NB * TIN, 512, 512);
  gemm_bf16<<<dim3(4, 4), 256, 0, stream>>>(xtr + 3ull * MROWS * 512, decw_bf, decp, dec_b,
                                            MROWS, 512, 512);
  tanha_kernel<<<20416, 256, 0, stream>>>(encp, decp, abuf);
  gemm_bf16<<<dim3(8, 638), 256, 0, stream>>>(abuf, outw_bf, Cout, nullptr, MJOINT, VSZ, 512);
}

// Round 4
// 531.977 us; speedup vs baseline: 2.4308x; 1.7580x over previous
//
#include <hip/hip_runtime.h>
#include <cstdint>
#include <cstddef>

typedef __attribute__((ext_vector_type(4))) float f32x4;
typedef __attribute__((ext_vector_type(8))) short bf16x8;      // MFMA operand (8 bf16)
typedef __attribute__((ext_vector_type(8))) unsigned short u16x8;
typedef __attribute__((ext_vector_type(4))) float float4v;
typedef __attribute__((ext_vector_type(2))) unsigned long long u64x2;
typedef unsigned long long ull;

// ---- problem dims ----
#define NB   8
#define TIN  200
#define TO1  51
#define VSZ  1024
#define HSZ  512
static constexpr int MJOINT = NB * TIN * TO1;   // 81600
static constexpr int MROWS  = TO1 * NB;         // 408  (rows t*8+n)

// ---- ws layout (bytes) ----
static constexpr size_t B_ENCBF = 0;                           // 1664*512*2
static constexpr size_t B_ENCW  = B_ENCBF + 1664ull*512*2;     // 512*512*2
static constexpr size_t B_DECW  = B_ENCW  + 512ull*512*2;
static constexpr size_t B_OUTW  = B_DECW  + 512ull*512*2;      // 1024*512*2
static constexpr size_t B_WIH   = B_OUTW  + 1024ull*512*2;     // 3*2048*512*2
static constexpr size_t B_WHH   = B_WIH   + 3ull*2048*512*2;
static constexpr size_t B_XTR   = B_WHH   + 3ull*2048*512*2;   // 4*408*512*2 (x0,h1,h2,h3 traces)
static constexpr size_t B_BSUM  = B_XTR   + 4ull*408*512*2;    // 3*2048*4
static constexpr size_t B_FLAGS = B_BSUM  + 3ull*2048*4;       // 96 flags x 64B = 6144 (pad 8192)
static constexpr size_t B_ENCP  = B_FLAGS + 8192;              // 1664*512*4
static constexpr size_t B_DECP  = B_ENCP  + 1664ull*512*4;     // 512*512*4
static constexpr size_t B_ABUF  = B_DECP  + 512ull*512*4;      // 81664*512*2

// ---- helpers ----
__device__ __forceinline__ unsigned short f2bf(float f) {
  union { float f; unsigned u; } v; v.f = f;
  unsigned r = v.u + 0x7FFFu + ((v.u >> 16) & 1u);
  return (unsigned short)(r >> 16);
}
__device__ __forceinline__ float fast_tanh(float x) {
  float t = __expf(2.0f * x);          // inf-safe: x>>0 -> 1, x<<0 -> -1
  return 1.0f - 2.0f / (t + 1.0f);
}
__device__ __forceinline__ float fast_sig(float x) {
  return 1.0f / (1.0f + __expf(-x));
}
__device__ __forceinline__ void gll16(const void* g, void* l) {
  __builtin_amdgcn_global_load_lds(
      (const __attribute__((address_space(1))) unsigned int*)g,
      (__attribute__((address_space(3))) unsigned int*)l, 16, 0, 0);
}
__device__ __forceinline__ void cvt8(const float* s, unsigned short* d) {
  const float4v* sp = (const float4v*)s;
  float4v x = sp[0], y = sp[1];
  u16x8 o;
  o[0]=f2bf(x[0]); o[1]=f2bf(x[1]); o[2]=f2bf(x[2]); o[3]=f2bf(x[3]);
  o[4]=f2bf(y[0]); o[5]=f2bf(y[1]); o[6]=f2bf(y[2]); o[7]=f2bf(y[3]);
  *(u16x8*)d = o;
}

// ---------------- fused fp32 -> bf16 convert for all weight/activation tensors ----------------
static constexpr int N_ENC  = 102400;           // 8*200*512/8
static constexpr int N_ENCW = 32768;
static constexpr int N_DECW = 32768;
static constexpr int N_OUTW = 65536;
static constexpr int N_WIH  = 393216;
static constexpr int P0 = N_ENC, P1 = P0+N_ENCW, P2 = P1+N_DECW, P3 = P2+N_OUTW,
                     P4 = P3+N_WIH;   // total 1019904 (=3984*256)

__global__ __launch_bounds__(256) void cvt_all(const float* __restrict__ enc,
                                               const float* __restrict__ encw,
                                               const float* __restrict__ decw,
                                               const float* __restrict__ outw,
                                               const float* __restrict__ wih,
                                               const float* __restrict__ whh,
                                               unsigned short* __restrict__ d_enc,
                                               unsigned short* __restrict__ d_encw,
                                               unsigned short* __restrict__ d_decw,
                                               unsigned short* __restrict__ d_outw,
                                               unsigned short* __restrict__ d_wih,
                                               unsigned short* __restrict__ d_whh) {
  int i = blockIdx.x * 256 + threadIdx.x;
  const float* s; unsigned short* d; int rel;
  if      (i < P0) { s = enc;  d = d_enc;  rel = i; }
  else if (i < P1) { s = encw; d = d_encw; rel = i - P0; }
  else if (i < P2) { s = decw; d = d_decw; rel = i - P1; }
  else if (i < P3) { s = outw; d = d_outw; rel = i - P2; }
  else if (i < P4) { s = wih;  d = d_wih;  rel = i - P3; }
  else             { s = whh;  d = d_whh;  rel = i - P4; }
  cvt8(s + (size_t)rel * 8, d + (size_t)rel * 8);
}

// ---------------- bias sum: bsum = b_ih + b_hh ----------------
__global__ __launch_bounds__(256) void bsum_kernel(const float* __restrict__ a,
                                                   const float* __restrict__ b,
                                                   float* __restrict__ o, int n) {
  int i = blockIdx.x * 256 + threadIdx.x;
  if (i < n) o[i] = a[i] + b[i];
}

// ---------------- embedding gather -> bf16 xtr[0][t*8+n][512] ----------------
__global__ __launch_bounds__(256) void embed_kernel(const float* __restrict__ emb,
                                                    const int* __restrict__ tgt,
                                                    unsigned short* __restrict__ x0) {
  int idx = blockIdx.x * 256 + threadIdx.x;   // 408*64
  if (idx >= MROWS * 64) return;
  int m = idx >> 6, kc = (idx & 63) * 8;
  int t = m >> 3, n = m & 7;
  int v = tgt[n * TO1 + t];
  cvt8(emb + (size_t)v * 512 + kc, x0 + (size_t)m * 512 + kc);
}

// ---------------- generic bf16 GEMM: C[M][N] = A[M][K] @ B[N][K]^T (+bias) ----------------
// 128x128 tile, BK=32, 4 waves each 64x64 (4x4 of 16x16x32 MFMA). XCD-swizzled block order.
__global__ __launch_bounds__(256) void gemm_bf16(const unsigned short* __restrict__ A,
                                                 const unsigned short* __restrict__ B,
                                                 float* __restrict__ C,
                                                 const float* __restrict__ bias,
                                                 int M, int N, int K) {
  __shared__ __align__(16) unsigned short As[128 * 32];
  __shared__ __align__(16) unsigned short Bs[128 * 32];
  const int tid = threadIdx.x;
  const int wave = tid >> 6, lane = tid & 63;
  const int lr = lane & 15, lk8 = (lane >> 4) * 8;
  const int wm = (wave >> 1) * 64, wn = (wave & 1) * 64;

  // bijective XCD-aware remap (m204 form): each XCD gets a contiguous id chunk
  const int nwg = gridDim.x * gridDim.y;
  const int id = blockIdx.y * gridDim.x + blockIdx.x;
  const int q = nwg >> 3, r = nwg & 7, xcd = id & 7, rest = id >> 3;
  const int nid = (xcd < r ? xcd * (q + 1) : r * (q + 1) + (xcd - r) * q) + rest;
  const size_t n0 = (size_t)(nid % gridDim.x) * 128;
  const size_t m0 = (size_t)(nid / gridDim.x) * 128;

  f32x4 acc[4][4];
#pragma unroll
  for (int i = 0; i < 4; ++i)
#pragma unroll
    for (int j = 0; j < 4; ++j) acc[i][j] = (f32x4){0.f, 0.f, 0.f, 0.f};

  const int c0 = tid, c1 = tid + 256;
  unsigned short* Asw = As + wave * 512;   // wave-uniform LDS base
  unsigned short* Bsw = Bs + wave * 512;

  for (int kt = 0; kt < K; kt += 32) {
    __syncthreads();
    gll16(A + (m0 + (size_t)(c0 >> 2)) * K + kt + (c0 & 3) * 8, Asw);
    gll16(A + (m0 + (size_t)(c1 >> 2)) * K + kt + (c1 & 3) * 8, Asw + 2048);
    gll16(B + (n0 + (size_t)(c0 >> 2)) * K + kt + (c0 & 3) * 8, Bsw);
    gll16(B + (n0 + (size_t)(c1 >> 2)) * K + kt + (c1 & 3) * 8, Bsw + 2048);
    __syncthreads();
    bf16x8 a[4], b[4];
#pragma unroll
    for (int i = 0; i < 4; ++i) a[i] = *(const bf16x8*)&As[(wm + i * 16 + lr) * 32 + lk8];
#pragma unroll
    for (int j = 0; j < 4; ++j) b[j] = *(const bf16x8*)&Bs[(wn + j * 16 + lr) * 32 + lk8];
#pragma unroll
    for (int i = 0; i < 4; ++i)
#pragma unroll
      for (int j = 0; j < 4; ++j)
        acc[i][j] = __builtin_amdgcn_mfma_f32_16x16x32_bf16(a[i], b[j], acc[i][j], 0, 0, 0);
  }

  const int rq = (lane >> 4) * 4;
#pragma unroll
  for (int j = 0; j < 4; ++j) {
    const int col = (int)n0 + wn + j * 16 + lr;
    const float bv = bias ? bias[col] : 0.0f;
#pragma unroll
    for (int i = 0; i < 4; ++i) {
#pragma unroll
      for (int q2 = 0; q2 < 4; ++q2) {
        const long m = (long)m0 + wm + i * 16 + rq + q2;
        if (m < M) C[(size_t)m * N + col] = acc[i][j][q2] + bv;
      }
    }
  }
}

// ---------------- fused 3-layer LSTM: fence-free fine-grained pipeline ----------------
// 96 blocks x 256 thr: layer l = blk/32; block owns 16 hidden units (hid0=(blk%32)*16).
// Weights [wih|whh] (64 gate rows x K=1024, bf16) live in LDS (128KB), loaded once.
// ALL cross-block traffic (h rows, flags) is relaxed agent-scope atomics (write-through,
// coherence-point served) -> ZERO cache-maintenance ops in the step loop.
__global__ __launch_bounds__(256) void rnn_kernel(const unsigned short* __restrict__ wih,
                                                  const unsigned short* __restrict__ whh,
                                                  const float* __restrict__ bsum,
                                                  unsigned short* __restrict__ xtr,
                                                  int* __restrict__ flags) {
  __shared__ __align__(16) unsigned short w_s[64 * 1024];   // 128 KB
  __shared__ __align__(16) unsigned short xh_s[8 * 1024];   // 16 KB  [row n][x(512)|h(512)]
  __shared__ float gates_s[4][8][16];

  const int tid = threadIdx.x;
  const int l = blockIdx.x >> 5;
  const int b32 = blockIdx.x & 31;
  const int hid0 = b32 << 4;
  const int wave = tid >> 6, lane = tid & 63;
  const int lr = lane & 15, lg = lane >> 4;   // fragment row (0..15), k-subgroup (0..3)
  const int r7 = lr & 7;

  // ---- load weight slice into LDS, XOR-swizzled (chunk c of 16B at c^(row&7)) ----
  {
    const int rl = tid >> 2;           // local row 0..63 (= gate*16 + unit)
    const int qt = tid & 3;            // quarter of the row
    const size_t R = (size_t)l * 2048 + (size_t)(rl >> 4) * 512 + hid0 + (rl & 15);
    const unsigned short* s0 = wih + R * 512;
    const unsigned short* s1 = whh + R * 512;
#pragma unroll
    for (int i = 0; i < 32; ++i) {
      int c = qt * 32 + i;
      bf16x8 wv = (c < 64) ? *(const bf16x8*)&s0[c * 8] : *(const bf16x8*)&s1[(c - 64) * 8];
      *(bf16x8*)&w_s[rl * 1024 + ((c ^ (rl & 7)) << 3)] = wv;
    }
  }
  const float bias = bsum[(size_t)l * 2048 + (size_t)wave * 512 + hid0 + lr];

  const unsigned short* xin = xtr + (size_t)l * MROWS * 512;
  unsigned short* xout = xtr + (size_t)(l + 1) * MROWS * 512;
  float c_reg = 0.f;                   // cell state (tid<128: n=tid>>4, j=tid&15)
  const int sr = tid >> 5;             // staging row 0..7
  const int sseg = tid & 31;           // staging 64B segment within 2KB row
  __syncthreads();

  for (int t = 0; t < TO1; ++t) {
    // ---- poll dependencies (wave0 only; no fences -- flags are coherent atomics) ----
    if (wave == 0) {
      const bool mine = lane < 32;
      const bool active = mine ? (t > 0) : (l > 0);
      const int fi = mine ? (l * 32 + lane) * 16 : ((l - 1) * 32 + (lane - 32)) * 16;
      const int need = mine ? t : t + 1;
      for (;;) {
        bool ok = true;
        if (active)
          ok = __hip_atomic_load(&flags[fi], __ATOMIC_RELAXED, __HIP_MEMORY_SCOPE_AGENT) >= need;
        if (__all(ok)) break;
        __builtin_amdgcn_s_sleep(1);
      }
    }
    __syncthreads();   // also protects xh_s reuse (prior compute finished)

    // ---- stage x(512)+h(512) rows via coherent atomic loads -> swizzled LDS ----
    {
      ull v[8];
      if (sseg < 16) {
        const ull* p = (const ull*)(xin + ((size_t)t * 8 + sr) * 512) + sseg * 8;
#pragma unroll
        for (int i = 0; i < 8; ++i)
          v[i] = __hip_atomic_load(p + i, __ATOMIC_RELAXED, __HIP_MEMORY_SCOPE_AGENT);
      } else if (t == 0) {
#pragma unroll
        for (int i = 0; i < 8; ++i) v[i] = 0ull;
      } else {
        const ull* p = (const ull*)(xout + ((size_t)(t - 1) * 8 + sr) * 512) + (sseg - 16) * 8;
#pragma unroll
        for (int i = 0; i < 8; ++i)
          v[i] = __hip_atomic_load(p + i, __ATOMIC_RELAXED, __HIP_MEMORY_SCOPE_AGENT);
      }
#pragma unroll
      for (int i2 = 0; i2 < 4; ++i2) {
        int c = sseg * 4 + i2;
        *(u64x2*)&xh_s[sr * 1024 + ((c ^ sr) << 3)] = (u64x2){v[2 * i2], v[2 * i2 + 1]};
      }
    }
    __syncthreads();

    // ---- 32 MFMAs per wave: gates[wave] for 16 units, batch 8 (rows 8..15 pad) ----
    {
      f32x4 acc0 = (f32x4){0.f, 0.f, 0.f, 0.f};
      f32x4 acc1 = (f32x4){0.f, 0.f, 0.f, 0.f};
      const int rw = wave * 16 + lr;
#pragma unroll
      for (int c32 = 0; c32 < 32; ++c32) {
        const int cc = c32 * 4 + lg;
        bf16x8 av = *(const bf16x8*)&xh_s[r7 * 1024 + ((cc ^ r7) << 3)];
        bf16x8 bv = *(const bf16x8*)&w_s[rw * 1024 + ((cc ^ r7) << 3)];
        if (c32 & 1) acc1 = __builtin_amdgcn_mfma_f32_16x16x32_bf16(av, bv, acc1, 0, 0, 0);
        else         acc0 = __builtin_amdgcn_mfma_f32_16x16x32_bf16(av, bv, acc0, 0, 0, 0);
      }
      f32x4 g = acc0 + acc1;
      const int nb4 = lg * 4;
#pragma unroll
      for (int q2 = 0; q2 < 4; ++q2) {
        int n = nb4 + q2;
        if (n < 8) gates_s[wave][n][lr] = g[q2] + bias;
      }
    }
    __syncthreads();

    // ---- nonlinearity + coherent h store (atomic write-through) ----
    if (tid < 128) {
      const int n = tid >> 4, j = tid & 15;
      float gi = gates_s[0][n][j], gf = gates_s[1][n][j];
      float gg = gates_s[2][n][j], go = gates_s[3][n][j];
      c_reg = fast_sig(gf) * c_reg + fast_sig(gi) * fast_tanh(gg);
      float ht = fast_sig(go) * fast_tanh(c_reg);
      float htn = __shfl_down(ht, 1);
      if (!(j & 1)) {
        unsigned pk = (unsigned)f2bf(ht) | ((unsigned)f2bf(htn) << 16);
        unsigned* dst = (unsigned*)(xout + ((size_t)t * 8 + n) * 512 + hid0 + j);
        __hip_atomic_store(dst, pk, __ATOMIC_RELAXED, __HIP_MEMORY_SCOPE_AGENT);
      }
    }
    asm volatile("s_waitcnt vmcnt(0)" ::: "memory");   // h at coherence point
    __syncthreads();                                   // ...for ALL waves
    if (tid == 0)
      __hip_atomic_store(&flags[(l * 32 + b32) * 16], t + 1,
                         __ATOMIC_RELAXED, __HIP_MEMORY_SCOPE_AGENT);
  }
}

// ---------------- A = tanh(enc_p + dec_p) -> bf16 [81664][512] ----------------
__global__ __launch_bounds__(256) void tanha_kernel(const float* __restrict__ encp,
                                                    const float* __restrict__ decp,
                                                    unsigned short* __restrict__ Ab) {
  size_t idx = (size_t)blockIdx.x * 256 + threadIdx.x;
  int m = (int)(idx >> 6);
  int kc = ((int)idx & 63) * 8;
  if (m >= 81664) return;
  u16x8 o;
  if (m >= MJOINT) {
    o[0]=0;o[1]=0;o[2]=0;o[3]=0;o[4]=0;o[5]=0;o[6]=0;o[7]=0;
  } else {
    int n = m / (TIN * TO1);
    int rem = m - n * (TIN * TO1);
    int t = rem / TO1;
    int u = rem - t * TO1;
    const float4v* ep = (const float4v*)(encp + ((size_t)n * TIN + t) * 512 + kc);
    const float4v* dp = (const float4v*)(decp + ((size_t)u * 8 + n) * 512 + kc);
    float4v e0 = ep[0], e1 = ep[1], d0 = dp[0], d1 = dp[1];
    o[0]=f2bf(fast_tanh(e0[0]+d0[0])); o[1]=f2bf(fast_tanh(e0[1]+d0[1]));
    o[2]=f2bf(fast_tanh(e0[2]+d0[2])); o[3]=f2bf(fast_tanh(e0[3]+d0[3]));
    o[4]=f2bf(fast_tanh(e1[0]+d1[0])); o[5]=f2bf(fast_tanh(e1[1]+d1[1]));
    o[6]=f2bf(fast_tanh(e1[2]+d1[2])); o[7]=f2bf(fast_tanh(e1[3]+d1[3]));
  }
  *(u16x8*)(Ab + (size_t)m * 512 + kc) = o;
}

// ---------------- launch ----------------
extern "C" void kernel_launch(void* const* d_in, const int* in_sizes, int n_in,
                              void* d_out, int out_size, void* d_ws, size_t ws_size,
                              hipStream_t stream) {
  (void)in_sizes; (void)n_in; (void)out_size; (void)ws_size;
  const float* enc_out = (const float*)d_in[0];
  const int*   tgt     = (const int*)d_in[1];
  const float* embed   = (const float*)d_in[2];
  const float* w_ih    = (const float*)d_in[3];
  const float* w_hh    = (const float*)d_in[4];
  const float* b_ih    = (const float*)d_in[5];
  const float* b_hh    = (const float*)d_in[6];
  const float* enc_w   = (const float*)d_in[7];
  const float* dec_w   = (const float*)d_in[8];
  const float* dec_b   = (const float*)d_in[9];
  const float* out_w   = (const float*)d_in[10];

  char* ws = (char*)d_ws;
  unsigned short* enc_bf  = (unsigned short*)(ws + B_ENCBF);
  unsigned short* encw_bf = (unsigned short*)(ws + B_ENCW);
  unsigned short* decw_bf = (unsigned short*)(ws + B_DECW);
  unsigned short* outw_bf = (unsigned short*)(ws + B_OUTW);
  unsigned short* wih_bf  = (unsigned short*)(ws + B_WIH);
  unsigned short* whh_bf  = (unsigned short*)(ws + B_WHH);
  unsigned short* xtr     = (unsigned short*)(ws + B_XTR);
  float* bsum  = (float*)(ws + B_BSUM);
  int*   flags = (int*)(ws + B_FLAGS);
  float* encp  = (float*)(ws + B_ENCP);
  float* decp  = (float*)(ws + B_DECP);
  unsigned short* abuf = (unsigned short*)(ws + B_ABUF);
  float* Cout  = (float*)d_out;

  hipMemsetAsync(flags, 0, 6144, stream);

  cvt_all<<<3984, 256, 0, stream>>>(enc_out, enc_w, dec_w, out_w, w_ih, w_hh,
                                    enc_bf, encw_bf, decw_bf, outw_bf, wih_bf, whh_bf);
  bsum_kernel<<<24, 256, 0, stream>>>(b_ih, b_hh, bsum, 6144);
  embed_kernel<<<102, 256, 0, stream>>>(embed, tgt, xtr);

  rnn_kernel<<<96, 256, 0, stream>>>(wih_bf, whh_bf, bsum, xtr, flags);

  gemm_bf16<<<dim3(4, 13), 256, 0, stream>>>(enc_bf, encw_bf, encp, nullptr, NB * TIN, 512, 512);
  gemm_bf16<<<dim3(4, 4), 256, 0, stream>>>(xtr + 3ull * MROWS * 512, decw_bf, decp, dec_b,
                                            MROWS, 512, 512);
  tanha_kernel<<<20416, 256, 0, stream>>>(encp, decp, abuf);
  gemm_bf16<<<dim3(8, 638), 256, 0, stream>>>(abuf, outw_bf, Cout, nullptr, MJOINT, VSZ, 512);
}